// Round 10
// baseline (351.951 us; speedup 1.0000x reference)
//
#include <hip/hip_runtime.h>
#include <hip/hip_bf16.h>
#include <stdint.h>

typedef _Float16 half8 __attribute__((ext_vector_type(8)));
typedef _Float16 half4 __attribute__((ext_vector_type(4)));
typedef float    f32x4 __attribute__((ext_vector_type(4)));

#define MFMA16(a, b, c) __builtin_amdgcn_mfma_f32_16x16x32_f16(a, b, c, 0, 0, 0)

// ---------------------------------------------------------------------------
// Generic fp32->fp16 transpose: X [R][C] fp32 -> Y [C][R] fp16, z-batched.
// ---------------------------------------------------------------------------
__global__ __launch_bounds__(256) void transpose_to_f16(
    const float* __restrict__ X, _Float16* __restrict__ Y,
    int R, int C, long inBS, long outBS)
{
    __shared__ float t[32][33];
    const int bz = blockIdx.z;
    X += (long)bz * inBS;
    Y += (long)bz * outBS;
    const int c0 = blockIdx.x * 32, r0 = blockIdx.y * 32;
    const int tx = threadIdx.x & 31, ty = threadIdx.x >> 5;
#pragma unroll
    for (int i = 0; i < 4; ++i)
        t[ty + i * 8][tx] = X[(long)(r0 + ty + i * 8) * C + c0 + tx];
    __syncthreads();
#pragma unroll
    for (int i = 0; i < 4; ++i)
        Y[(long)(c0 + ty + i * 8) * R + r0 + tx] = (_Float16)t[tx][ty + i * 8];
}

// ---------------------------------------------------------------------------
// MFMA GEMM v2 (unchanged from R9-passing). C[M,N] = A[M,K](fp32) @ BT[N,K].
// Batched staging loads; optional dual-input fusion (A1) and split-K atomics.
// ---------------------------------------------------------------------------
__global__ __launch_bounds__(256, 2) void gemm_f16_v2(
    const float* __restrict__ A0, const float* __restrict__ A1,
    const _Float16* __restrict__ BT,
    const float* __restrict__ bias0, const float* __restrict__ bias1,
    void* __restrict__ Cout,
    int N, int lda, int ldbt, int ldc,
    long aBS, long bBS, long cBS,
    int c_half, int atomic, int nks, int kchunk)
{
    __shared__ __align__(16) _Float16 As[128][72];
    __shared__ __align__(16) _Float16 Bs[128][72];

    const int nt = blockIdx.x, mt = blockIdx.y;
    const int b = blockIdx.z / nks, ks = blockIdx.z % nks;
    const int kbeg = ks * kchunk;

    const float* A = A1 ? (b ? A1 : A0) : (A0 + (long)b * aBS);
    const _Float16* Bb = BT + (long)b * bBS;

    const int n0 = nt * 128;
    const int m0 = mt * 128;
    const int tid  = threadIdx.x;
    const int wave = tid >> 6, lane = tid & 63;
    const int m16  = lane & 15, quad = lane >> 4;

    f32x4 acc[2][8];
    {
        f32x4 z = {0.f, 0.f, 0.f, 0.f};
#pragma unroll
        for (int i = 0; i < 2; ++i)
#pragma unroll
            for (int j = 0; j < 8; ++j) acc[i][j] = z;
    }

    for (int k0 = kbeg; k0 < kbeg + kchunk; k0 += 64) {
        // ---- stage A tile: batch 8 loads, then convert+write
        {
            const int cc = (tid & 15) * 4;
            const int rb = tid >> 4;
            float4 av[8];
#pragma unroll
            for (int p = 0; p < 8; ++p)
                av[p] = *(const float4*)(A + (long)(m0 + rb + p * 16) * lda + k0 + cc);
#pragma unroll
            for (int p = 0; p < 8; ++p) {
                half4 hv;
                hv[0] = (_Float16)av[p].x; hv[1] = (_Float16)av[p].y;
                hv[2] = (_Float16)av[p].z; hv[3] = (_Float16)av[p].w;
                *(half4*)&As[rb + p * 16][cc] = hv;
            }
        }
        // ---- stage B tile: batch 4 loads, then write
        {
            const int j  = tid >> 1;
            const int cc = (tid & 1) * 32;
            int jn = n0 + j; if (jn > N - 1) jn = N - 1;
            const _Float16* bp = Bb + (long)jn * ldbt + k0 + cc;
            half8 b0 = *(const half8*)(bp);
            half8 b1 = *(const half8*)(bp + 8);
            half8 b2 = *(const half8*)(bp + 16);
            half8 b3 = *(const half8*)(bp + 24);
            *(half8*)&Bs[j][cc]      = b0;
            *(half8*)&Bs[j][cc + 8]  = b1;
            *(half8*)&Bs[j][cc + 16] = b2;
            *(half8*)&Bs[j][cc + 24] = b3;
        }
        __syncthreads();
#pragma unroll
        for (int kss = 0; kss < 2; ++kss) {
            const int ko = kss * 32 + quad * 8;
            const half8 a0 = *(const half8*)&As[wave * 32 + m16][ko];
            const half8 a1 = *(const half8*)&As[wave * 32 + 16 + m16][ko];
#pragma unroll
            for (int c = 0; c < 8; ++c) {
                const half8 bf = *(const half8*)&Bs[c * 16 + m16][ko];
                acc[0][c] = MFMA16(a0, bf, acc[0][c]);
                acc[1][c] = MFMA16(a1, bf, acc[1][c]);
            }
        }
        __syncthreads();
    }

    // ---- epilogue: C/D layout col=lane&15, row=quad*4+r
    const float* bias = b ? bias1 : bias0;
    const int addb = (bias != nullptr) && (kbeg == 0);
#pragma unroll
    for (int hh = 0; hh < 2; ++hh) {
#pragma unroll
        for (int c = 0; c < 8; ++c) {
            const int col = n0 + c * 16 + m16;
            if (col >= N) continue;
            const float bb = addb ? bias[col] : 0.f;
#pragma unroll
            for (int r = 0; r < 4; ++r) {
                const int row = m0 + wave * 32 + hh * 16 + quad * 4 + r;
                const float v = acc[hh][c][r] + bb;
                const long idx = (long)b * cBS + (long)row * ldc + col;
                if (atomic)      atomicAdd(&((float*)Cout)[idx], v);
                else if (c_half) ((_Float16*)Cout)[idx] = (_Float16)v;
                else             ((float*)Cout)[idx] = v;
            }
        }
    }
}

// ---------------------------------------------------------------------------
// Pass 1 v2: per (b,h,s) row stats. R9 evidence: latency-serialized loads
// (MfmaUtil 2%, VALUBusy 8%, HBM 8%). Now processes 4 t-tiles per group
// (8 batched k-loads) and prefetches the next group during compute; groups
// strictly below the diagonal skip the col<=row predicate.
// ---------------------------------------------------------------------------
__global__ __launch_bounds__(256, 2) void attn_stats(
    const _Float16* __restrict__ q_all, const _Float16* __restrict__ k_all,
    float* __restrict__ m_out, float* __restrict__ il_out)
{
    const int st = blockIdx.x, h = blockIdx.y, b = blockIdx.z;
    const int tid = threadIdx.x, wave = tid >> 6, lane = tid & 63;
    const int m16 = lane & 15, quad = lane >> 4;
    const int s0 = st * 64 + wave * 16;

    const _Float16* qp = q_all + ((long)(b * 1024 + s0 + m16)) * 1024 + h * 64 + quad * 8;
    const half8 a0 = *(const half8*)qp;
    const half8 a1 = *(const half8*)(qp + 32);

    float mr[4], lr[4];
#pragma unroll
    for (int r = 0; r < 4; ++r) { mr[r] = -3.0e38f; lr[r] = 0.f; }

    const _Float16* kb = k_all + ((long)(b * 1024 + m16)) * 1024 + h * 64 + quad * 8;
    const int ngroups = st + 1;   // groups of 4 tiles (64 cols each)

    half8 cur[4][2], nxt[4][2];
#pragma unroll
    for (int t = 0; t < 4; ++t) {
        const _Float16* kp = kb + (long)(t * 16) * 1024;
        cur[t][0] = *(const half8*)kp;
        cur[t][1] = *(const half8*)(kp + 32);
    }

    for (int g = 0; g < ngroups; ++g) {
        if (g + 1 < ngroups) {
#pragma unroll
            for (int t = 0; t < 4; ++t) {
                const _Float16* kp = kb + (long)((g + 1) * 64 + t * 16) * 1024;
                nxt[t][0] = *(const half8*)kp;
                nxt[t][1] = *(const half8*)(kp + 32);
            }
        }
        if (g < st) {
            // fully below diagonal: no mask
#pragma unroll
            for (int t = 0; t < 4; ++t) {
                f32x4 c = {0.f, 0.f, 0.f, 0.f};
                c = MFMA16(a0, cur[t][0], c);
                c = MFMA16(a1, cur[t][1], c);
#pragma unroll
                for (int r = 0; r < 4; ++r) {
                    const float z  = c[r] * 0.125f;
                    const float nm = fmaxf(mr[r], z);
                    lr[r] = lr[r] * __expf(mr[r] - nm) + __expf(z - nm);
                    mr[r] = nm;
                }
            }
        } else {
            // diagonal group: predicated
#pragma unroll
            for (int t = 0; t < 4; ++t) {
                f32x4 c = {0.f, 0.f, 0.f, 0.f};
                c = MFMA16(a0, cur[t][0], c);
                c = MFMA16(a1, cur[t][1], c);
                const int col = g * 64 + t * 16 + m16;
#pragma unroll
                for (int r = 0; r < 4; ++r) {
                    const int row = s0 + quad * 4 + r;
                    if (col <= row) {
                        const float z  = c[r] * 0.125f;
                        const float nm = fmaxf(mr[r], z);
                        lr[r] = lr[r] * __expf(mr[r] - nm) + __expf(z - nm);
                        mr[r] = nm;
                    }
                }
            }
        }
#pragma unroll
        for (int t = 0; t < 4; ++t) { cur[t][0] = nxt[t][0]; cur[t][1] = nxt[t][1]; }
    }

    // merge across the 16 lanes sharing each row (same quad)
#pragma unroll
    for (int mk = 1; mk < 16; mk <<= 1) {
#pragma unroll
        for (int r = 0; r < 4; ++r) {
            const float om = __shfl_xor(mr[r], mk);
            const float ol = __shfl_xor(lr[r], mk);
            const float nm = fmaxf(mr[r], om);
            lr[r] = lr[r] * __expf(mr[r] - nm) + ol * __expf(om - nm);
            mr[r] = nm;
        }
    }
    if (m16 == 0) {
#pragma unroll
        for (int r = 0; r < 4; ++r) {
            const long idx = ((long)(b * 16 + h)) * 1024 + s0 + quad * 4 + r;
            m_out[idx]  = mr[r];
            il_out[idx] = 1.f / lr[r];
        }
    }
}

// ---------------------------------------------------------------------------
// Pass 2 v2: attn_mean = (1/H) sum_h softmax. Software-pipelined over heads:
// prefetch head h+1's q-frags, 8 k-frags, and m/il while computing head h
// (one vmcnt wait per head instead of ~4 serial chains). Sub-diagonal blocks
// skip the col<=row predicate. Upper-triangle tiles zero-fill.
// ---------------------------------------------------------------------------
__global__ __launch_bounds__(256, 2) void attn_pmean(
    const _Float16* __restrict__ q_all, const _Float16* __restrict__ k_all,
    const float* __restrict__ m_in, const float* __restrict__ il_in,
    float* __restrict__ attn)
{
    const int ttile = blockIdx.x, stile = blockIdx.y, b = blockIdx.z;
    const int tid = threadIdx.x;
    if (ttile > stile) {
        const int c4 = (tid & 15) * 4;
        float4 z = {0.f, 0.f, 0.f, 0.f};
#pragma unroll
        for (int i = 0; i < 4; ++i) {
            const int r = stile * 64 + (tid >> 4) + i * 16;
            *(float4*)&attn[((long)(b * 1024 + r)) * 1024 + ttile * 64 + c4] = z;
        }
        return;
    }
    const int wave = tid >> 6, lane = tid & 63;
    const int m16 = lane & 15, quad = lane >> 4;
    const int s0 = stile * 64 + wave * 16;
    const int t0 = ttile * 64;
    const int diag = (ttile == stile);

    const _Float16* qbase = q_all + ((long)(b * 1024 + s0 + m16)) * 1024 + quad * 8;
    const _Float16* kbase = k_all + ((long)(b * 1024 + t0 + m16)) * 1024 + quad * 8;
    const long sbase = ((long)(b * 16)) * 1024 + s0 + quad * 4;

    float pm[4][4];
#pragma unroll
    for (int c = 0; c < 4; ++c)
#pragma unroll
        for (int r = 0; r < 4; ++r) pm[c][r] = 0.f;

    half8 qa[2], qn[2];
    half8 kc[4][2], kn[4][2];
    float mc[4], ic[4], mn[4], inx[4];

    // prefetch head 0
    qa[0] = *(const half8*)(qbase);
    qa[1] = *(const half8*)(qbase + 32);
#pragma unroll
    for (int c = 0; c < 4; ++c) {
        const _Float16* kp = kbase + (long)(c * 16) * 1024;
        kc[c][0] = *(const half8*)kp;
        kc[c][1] = *(const half8*)(kp + 32);
    }
#pragma unroll
    for (int r = 0; r < 4; ++r) {
        mc[r] = m_in[sbase + r];
        ic[r] = il_in[sbase + r];
    }

    for (int h = 0; h < 16; ++h) {
        if (h < 15) {
            const int ho = (h + 1) * 64;
            qn[0] = *(const half8*)(qbase + ho);
            qn[1] = *(const half8*)(qbase + ho + 32);
#pragma unroll
            for (int c = 0; c < 4; ++c) {
                const _Float16* kp = kbase + (long)(c * 16) * 1024 + ho;
                kn[c][0] = *(const half8*)kp;
                kn[c][1] = *(const half8*)(kp + 32);
            }
            const long idxn = sbase + (long)(h + 1) * 1024;
#pragma unroll
            for (int r = 0; r < 4; ++r) {
                mn[r]  = m_in[idxn + r];
                inx[r] = il_in[idxn + r];
            }
        }
        if (!diag) {
#pragma unroll
            for (int c = 0; c < 4; ++c) {
                f32x4 cc = {0.f, 0.f, 0.f, 0.f};
                cc = MFMA16(qa[0], kc[c][0], cc);
                cc = MFMA16(qa[1], kc[c][1], cc);
#pragma unroll
                for (int r = 0; r < 4; ++r)
                    pm[c][r] += __expf(cc[r] * 0.125f - mc[r]) * ic[r];
            }
        } else {
#pragma unroll
            for (int c = 0; c < 4; ++c) {
                f32x4 cc = {0.f, 0.f, 0.f, 0.f};
                cc = MFMA16(qa[0], kc[c][0], cc);
                cc = MFMA16(qa[1], kc[c][1], cc);
                const int col = t0 + c * 16 + m16;
#pragma unroll
                for (int r = 0; r < 4; ++r) {
                    const int row = s0 + quad * 4 + r;
                    if (col <= row)
                        pm[c][r] += __expf(cc[r] * 0.125f - mc[r]) * ic[r];
                }
            }
        }
        // rotate prefetch buffers
        qa[0] = qn[0]; qa[1] = qn[1];
#pragma unroll
        for (int c = 0; c < 4; ++c) { kc[c][0] = kn[c][0]; kc[c][1] = kn[c][1]; }
#pragma unroll
        for (int r = 0; r < 4; ++r) { mc[r] = mn[r]; ic[r] = inx[r]; }
    }

#pragma unroll
    for (int c = 0; c < 4; ++c) {
#pragma unroll
        for (int r = 0; r < 4; ++r) {
            const int row = s0 + quad * 4 + r;
            const int col = t0 + c * 16 + m16;
            attn[((long)(b * 1024 + row)) * 1024 + col] = pm[c][r] * 0.0625f;
        }
    }
}

// ---------------------------------------------------------------------------
extern "C" void kernel_launch(void* const* d_in, const int* in_sizes, int n_in,
                              void* d_out, int out_size, void* d_ws, size_t ws_size,
                              hipStream_t stream)
{
    const float* queries = (const float*)d_in[0];
    const float* keys    = (const float*)d_in[1];
    const float* values  = (const float*)d_in[2];
    const float* Wq = (const float*)d_in[4];
    const float* bq = (const float*)d_in[5];
    const float* Wk = (const float*)d_in[6];
    const float* bk = (const float*)d_in[7];
    const float* Wv = (const float*)d_in[8];
    const float* bv = (const float*)d_in[9];
    const float* Wo = (const float*)d_in[10];
    const float* bo = (const float*)d_in[11];

    float* out_ptr  = (float*)d_out;                   // [4096][1024]
    float* attn_ptr = out_ptr + (long)4096 * 1024;     // [4][1024][1024]

    uint8_t* w = (uint8_t*)d_ws;
    size_t off = 0;
    auto alloc = [&](size_t bytes) {
        void* p = w + off;
        off = (off + bytes + 255) & ~(size_t)255;
        return p;
    };
    _Float16* WqkT  = (_Float16*)alloc((size_t)2 * 1024 * 1024 * 2); // WqT|WkT [n][d]
    _Float16* WvT   = (_Float16*)alloc((size_t)64 * 1024 * 2);       // [e][d]
    _Float16* WoT   = (_Float16*)alloc((size_t)1024 * 64 * 2);       // [d][e]
    _Float16* qkall = (_Float16*)alloc((size_t)2 * 4194304 * 2);     // qall|kall
    float*    vbuf  = (float*)alloc((size_t)4096 * 64 * 4);
    _Float16* vT    = (_Float16*)alloc((size_t)4 * 64 * 1024 * 2);   // per-b [e][t]
    float*    ctx   = (float*)alloc((size_t)4096 * 64 * 4);
    float*    mbuf  = (float*)alloc((size_t)65536 * 4);
    float*    ilbuf = (float*)alloc((size_t)65536 * 4);
    (void)ws_size; (void)in_sizes; (void)n_in; (void)out_size;

    _Float16* qall = qkall;
    _Float16* kall = qkall + (long)4194304;

    // weight transposes/conversions
    transpose_to_f16<<<dim3(2, 32, 16), 256, 0, stream>>>(Wq, WqkT, 1024, 64, 65536, 65536);
    transpose_to_f16<<<dim3(2, 32, 16), 256, 0, stream>>>(Wk, WqkT + (long)1024 * 1024, 1024, 64, 65536, 65536);
    transpose_to_f16<<<dim3(2, 32, 1),  256, 0, stream>>>(Wv, WvT, 1024, 64, 0, 0);
    transpose_to_f16<<<dim3(32, 2, 1),  256, 0, stream>>>(Wo, WoT, 64, 1024, 0, 0);

    // fused q+k projection: z selects queries/Wq/bq vs keys/Wk/bk; 512 blocks
    gemm_f16_v2<<<dim3(8, 32, 2), 256, 0, stream>>>(
        queries, keys, WqkT, bq, bk, qkall,
        1024, 1024, 1024, 1024,
        0, (long)1048576, (long)4194304,
        /*c_half=*/1, /*atomic=*/0, /*nks=*/1, /*kchunk=*/1024);

    // v projection: split-K x8 atomic into vbuf (zeroed) -> 256 blocks
    hipMemsetAsync(vbuf, 0, (size_t)4096 * 64 * 4, stream);
    gemm_f16_v2<<<dim3(1, 32, 8), 256, 0, stream>>>(
        values, nullptr, WvT, bv, nullptr, vbuf,
        64, 1024, 1024, 64,
        0, 0, 0,
        /*c_half=*/0, /*atomic=*/1, /*nks=*/8, /*kchunk=*/128);

    // vT per batch: [1024][64] -> [64][1024] fp16
    transpose_to_f16<<<dim3(2, 32, 4), 256, 0, stream>>>(vbuf, vT, 1024, 64, 65536, 65536);

    // softmax stats then head-averaged probabilities (writes full attn)
    attn_stats<<<dim3(16, 16, 4), 256, 0, stream>>>(qall, kall, mbuf, ilbuf);
    attn_pmean<<<dim3(16, 16, 4), 256, 0, stream>>>(qall, kall, mbuf, ilbuf, attn_ptr);

    // ctx[b] = attn_mean[b] @ v[b]: batch x split-K x8 atomic -> 256 blocks
    hipMemsetAsync(ctx, 0, (size_t)4096 * 64 * 4, stream);
    gemm_f16_v2<<<dim3(1, 8, 32), 256, 0, stream>>>(
        attn_ptr, nullptr, vT, nullptr, nullptr, ctx,
        64, 1024, 1024, 64,
        (long)1048576, (long)65536, (long)65536,
        /*c_half=*/0, /*atomic=*/1, /*nks=*/8, /*kchunk=*/128);

    // out = ctx @ Wo + bo (K=64: single iteration)
    gemm_f16_v2<<<dim3(8, 32, 1), 256, 0, stream>>>(
        ctx, nullptr, WoT, bo, nullptr, out_ptr,
        1024, 64, 64, 1024,
        0, 0, 0,
        /*c_half=*/0, /*atomic=*/0, /*nks=*/1, /*kchunk=*/64);
}